// Round 19
// baseline (172.758 us; speedup 1.0000x reference)
//
#include <hip/hip_runtime.h>
#include <hip/hip_bf16.h>

typedef __bf16 bf16x8 __attribute__((ext_vector_type(8)));
typedef __bf16 bf16x4 __attribute__((ext_vector_type(4)));
typedef float  f32x4  __attribute__((ext_vector_type(4)));
typedef unsigned short u16;
typedef unsigned int   u32;

#define GLOBAL_AS __attribute__((address_space(1)))
#define LDS_AS    __attribute__((address_space(3)))

#define LOG2E 1.44269504088896f

__device__ __forceinline__ void gload_lds16(const void* g, void* l) {
    __builtin_amdgcn_global_load_lds((GLOBAL_AS void*)g, (LDS_AS void*)l, 16, 0, 0);
}

__device__ __forceinline__ u16 f2b(float f) {
    union { float f; u32 u; } c; c.f = f;
    u32 u = c.u;
    u32 r = (u + 0x7FFFu + ((u >> 16) & 1u)) >> 16;   // RNE
    return (u16)r;
}

// XCD-locality block remap (bijective; assumes HW round-robin dispatch -> XCD = flat%8,
// perf-only heuristic). Blocks sharing a Y-panel land on one XCD. Requires gridDim.y%8==0.
__device__ __forceinline__ int2 xcd_remap() {
    int j   = blockIdx.x + blockIdx.y * gridDim.x;
    int xcd = j & 7, s = j >> 3;
    int by  = xcd * (gridDim.y >> 3) + s / gridDim.x;
    int bx  = s % gridDim.x;
    return make_int2(bx, by);
}

// ---------------- weight prep ----------------

// All 4 weight transposes (768x768 f32 -> bf16, dst[j][k]=src[k][j]) + bias pack in ONE launch.
__global__ void wprep_kernel(const float* __restrict__ Wq, const float* __restrict__ Wk,
                             const float* __restrict__ Wv, const float* __restrict__ Wo,
                             const float* __restrict__ bq, const float* __restrict__ bk,
                             const float* __restrict__ bv,
                             u16* __restrict__ WqkvT, u16* __restrict__ WoT,
                             float* __restrict__ bqkv) {
    __shared__ float tile[32][33];
    const int z = blockIdx.z;
    const float* src = (z == 0) ? Wq : (z == 1) ? Wk : (z == 2) ? Wv : Wo;
    u16* dst = (z == 3) ? WoT : WqkvT + (size_t)z * 768 * 768;
    int jt = blockIdx.x * 32, kt = blockIdx.y * 32;
    int tx = threadIdx.x, ty = threadIdx.y;           // block (32,8)
#pragma unroll
    for (int i = 0; i < 4; ++i)
        tile[ty + i * 8][tx] = src[(size_t)(kt + ty + i * 8) * 768 + jt + tx];
    __syncthreads();
#pragma unroll
    for (int i = 0; i < 4; ++i)
        dst[(size_t)(jt + ty + i * 8) * 768 + kt + tx] = f2b(tile[tx][ty + i * 8]);
    if (z == 0 && blockIdx.x == 0 && blockIdx.y == 0) {
        for (int i = ty * 32 + tx; i < 2304; i += 256)
            bqkv[i] = (i < 768) ? bq[i] : (i < 1536 ? bk[i - 768] : bv[i - 1536]);
    }
}

// ---------------- GEMM1 128x128: C = x(f32) @ Bt^T + bias, fused f32->bf16 A-staging ----
// A-side: reg-staged from f32 x (per k-step each thread stages FOUR 16B chunks: 8 x f32x4
// loads -> cvt -> 4 x ds_write_b128, swizzled; consecutive lanes hit consecutive chunks ->
// conflict-free). R18 bug was staging only 512 of 1024 chunks. Deletes the cvt_x pass.
// B-side: gload_lds with pre-swizzled source. XCD-remapped. VSPLIT epilogue: cols
// [0,1536) -> C; cols [1536,2304) -> VT[col-1536][perm(row)], p=(r&35)+((r&12)<<1)+((r&16)>>2).
__global__ __launch_bounds__(256) void gemm_x_kernel(
    const float* __restrict__ X, const u16* __restrict__ Bt,
    const float* __restrict__ bias, u16* __restrict__ C, u16* __restrict__ VT,
    int M, int N, int K, int ldc)
{
    __shared__ u16 As[128 * 64];
    __shared__ u16 Bs[128 * 64];
    const int lane = threadIdx.x & 63;
    const int w    = threadIdx.x >> 6;
    const int g    = lane >> 4;
    const int l15  = lane & 15;
    const int wr   = w >> 1, wc = w & 1;              // 2x2 waves -> 64x64 each
    const int2 bc  = xcd_remap();
    const int m0   = bc.y * 128, n0 = bc.x * 128;

    f32x4 acc[4][4] = {};

    for (int k0 = 0; k0 < K; k0 += 64) {
        __syncthreads();
        // B first: async gload_lds (latency hides under A's reg-staging VALU work)
#pragma unroll
        for (int i = 0; i < 4; ++i) {
            int ci0 = w * 64 + i * 256;
            int ci  = ci0 + lane;
            int row = ci >> 3;
            int col = ((ci & 7) ^ (row & 7)) << 3;
            gload_lds16(Bt + (size_t)(n0 + row) * K + k0 + col, (void*)(Bs + ci0 * 8));
        }
        // A: reg-stage f32 -> bf16 (4 chunks per thread = all 1024 chunks)
#pragma unroll
        for (int i = 0; i < 4; ++i) {
            int ci  = w * 64 + lane + i * 256;        // chunk index 0..1023
            int row = ci >> 3;
            int cc  = (ci & 7) ^ (row & 7);           // swizzled chunk within row
            const float* src = X + (size_t)(m0 + row) * K + k0 + cc * 8;
            f32x4 a = *(const f32x4*)src;
            f32x4 b = *(const f32x4*)(src + 4);
            u16 o[8];
#pragma unroll
            for (int j = 0; j < 4; ++j) { o[j] = f2b(a[j]); o[j + 4] = f2b(b[j]); }
            *(uint4*)&As[(row * 8 + (ci & 7)) * 8] = *(uint4*)o;
        }
        asm volatile("s_waitcnt vmcnt(0)" ::: "memory");
        __syncthreads();

#pragma unroll
        for (int ks = 0; ks < 2; ++ks) {
            const int cb = ks * 4 + g;                // chunk index of this fragment
            bf16x8 af[4], bfr[4];
#pragma unroll
            for (int i = 0; i < 4; ++i) {
                int row = wr * 64 + i * 16 + l15;
                af[i] = *(const bf16x8*)&As[row * 64 + ((cb ^ (row & 7)) << 3)];
            }
#pragma unroll
            for (int j = 0; j < 4; ++j) {
                int row = wc * 64 + j * 16 + l15;
                bfr[j] = *(const bf16x8*)&Bs[row * 64 + ((cb ^ (row & 7)) << 3)];
            }
#pragma unroll
            for (int i = 0; i < 4; ++i)
#pragma unroll
                for (int j = 0; j < 4; ++j)
                    acc[i][j] = __builtin_amdgcn_mfma_f32_16x16x32_bf16(af[i], bfr[j], acc[i][j], 0, 0, 0);
        }
    }

    const bool vblk = (n0 >= 1536);                   // uniform per block (1536 % 128 == 0)
#pragma unroll
    for (int j = 0; j < 4; ++j) {
        int col = n0 + wc * 64 + j * 16 + l15;
        float bv = bias[col];
#pragma unroll
        for (int i = 0; i < 4; ++i) {
            int row = m0 + wr * 64 + i * 16 + (g << 2);
            if (vblk) {
                u16 o[4];
#pragma unroll
                for (int r = 0; r < 4; ++r) o[r] = f2b(acc[i][j][r] + bv);
                int rl = row & 63;
                int pr = (row & ~63) + (rl & 35) + ((rl & 12) << 1) + ((rl & 16) >> 2);
                *(uint2*)(VT + (size_t)(col - 1536) * 8192 + pr) = *(uint2*)o;
            } else {
#pragma unroll
                for (int r = 0; r < 4; ++r)
                    C[(size_t)(row + r) * ldc + col] = f2b(acc[i][j][r] + bv);
            }
        }
    }
}

// ---------------- GEMM 64x128 (f32 out), XOR-swizzled LDS, XCD-remapped ----------------
__global__ __launch_bounds__(256) void gemm_bt64_kernel(
    const u16* __restrict__ A, const u16* __restrict__ Bt,
    const float* __restrict__ bias, float* __restrict__ C,
    int M, int N, int K, int ldc)
{
    __shared__ u16 As[64 * 64];                       // 8 KB
    __shared__ u16 Bs[128 * 64];                      // 16 KB
    const int lane = threadIdx.x & 63;
    const int w    = threadIdx.x >> 6;
    const int g    = lane >> 4;
    const int l15  = lane & 15;
    const int wr   = w >> 1, wc = w & 1;              // 2x2 waves -> 32x64 each
    const int2 bc  = xcd_remap();
    const int m0   = bc.y * 64, n0 = bc.x * 128;

    f32x4 acc[2][4] = {};

    for (int k0 = 0; k0 < K; k0 += 64) {
        __syncthreads();
#pragma unroll
        for (int i = 0; i < 2; ++i) {
            int ci0 = w * 64 + i * 256;
            int ci  = ci0 + lane;
            int row = ci >> 3;
            int col = ((ci & 7) ^ (row & 7)) << 3;
            gload_lds16(A + (size_t)(m0 + row) * K + k0 + col, (void*)(As + ci0 * 8));
        }
#pragma unroll
        for (int i = 0; i < 4; ++i) {
            int ci0 = w * 64 + i * 256;
            int ci  = ci0 + lane;
            int row = ci >> 3;
            int col = ((ci & 7) ^ (row & 7)) << 3;
            gload_lds16(Bt + (size_t)(n0 + row) * K + k0 + col, (void*)(Bs + ci0 * 8));
        }
        asm volatile("s_waitcnt vmcnt(0)" ::: "memory");
        __syncthreads();

#pragma unroll
        for (int ks = 0; ks < 2; ++ks) {
            const int cb = ks * 4 + g;
            bf16x8 af[2], bfr[4];
#pragma unroll
            for (int i = 0; i < 2; ++i) {
                int row = wr * 32 + i * 16 + l15;
                af[i] = *(const bf16x8*)&As[row * 64 + ((cb ^ (row & 7)) << 3)];
            }
#pragma unroll
            for (int j = 0; j < 4; ++j) {
                int row = wc * 64 + j * 16 + l15;
                bfr[j] = *(const bf16x8*)&Bs[row * 64 + ((cb ^ (row & 7)) << 3)];
            }
#pragma unroll
            for (int i = 0; i < 2; ++i)
#pragma unroll
                for (int j = 0; j < 4; ++j)
                    acc[i][j] = __builtin_amdgcn_mfma_f32_16x16x32_bf16(af[i], bfr[j], acc[i][j], 0, 0, 0);
        }
    }

#pragma unroll
    for (int j = 0; j < 4; ++j) {
        int col = n0 + wc * 64 + j * 16 + l15;
        float bv = bias[col];
#pragma unroll
        for (int i = 0; i < 2; ++i) {
            int row = m0 + wr * 32 + i * 16 + (g << 2);
#pragma unroll
            for (int r = 0; r < 4; ++r)
                C[(size_t)(row + r) * ldc + col] = acc[i][j][r] + bv;
        }
    }
}

// ---------------- flash attention (R16 exact: best known, 89-92 us) ----------------
// 512-thread blocks (8 waves x 16 q), QBLK=128, KVBLK=64, grid (16,48)=768 = 3 blocks/CU,
// LDS 32 KB (capacity 5). XCD remap: K/V L2-resident (FETCH 18.5 MB). Swapped QK^T,
// lane-local P via permuted VT, unshifted exp2 softmax, dbuf K/V, 1 barrier/iter,
// zero bank conflicts, static LDS indexing (R17's runtime-indexed 3-buffer regressed).
__global__ __launch_bounds__(512) void attn_kernel(
    const u16* __restrict__ QK, const u16* __restrict__ VT,
    const float* __restrict__ mask, u16* __restrict__ Comb)
{
    __shared__ u16 Ks[2][64 * 64];     // 16 KB
    __shared__ u16 Vs[2][64 * 64];     // 16 KB  -> total 32 KB
    const int lane = threadIdx.x & 63;
    const int w    = threadIdx.x >> 6;                // 0..7
    const int g    = lane >> 4;
    const int l15  = lane & 15;
    const int l7   = lane & 7;
    const int2 bc  = xcd_remap();
    const int q0   = bc.x * 128;
    const int bh   = bc.y;
    const int b    = bh / 12, h = bh % 12;
    const size_t rowbase = (size_t)b * 2048;
    const u16* Qg = QK + rowbase * 1536 + h * 64;
    const u16* Kg = QK + rowbase * 1536 + 768 + h * 64;
    const u16* Vg = VT + (size_t)(h * 64) * 8192 + b * 2048;  // row d (stride 8192), col s'
    const float* mbase = mask + b * 2048 + (g << 2);

    // staging: 512 threads cover 512 chunks (one 16B chunk each)
    const int sci  = threadIdx.x;
    const int srow = sci >> 3;                        // k-row / d-row
    const int kc   = ((sci & 7) ^ (srow & 7)) << 3;   // swizzle col
    const u16* kg0 = Kg + (size_t)srow * 1536 + kc;
    const u16* vg0 = Vg + (size_t)srow * 8192 + kc;
    u16* const ksd0 = (u16*)Ks + (w * 64) * 8;        // wave-uniform base + lane*16B
    u16* const vsd0 = (u16*)Vs + (w * 64) * 8;

    // prologue: stage K/V tile 0
    gload_lds16(kg0, (void*)ksd0);
    gload_lds16(vg0, (void*)vsd0);

    // Q fragments scaled by 0.125 * log2(e); wave owns rows q0 + w*16 .. +15
    bf16x8 qf[2];
#pragma unroll
    for (int ks = 0; ks < 2; ++ks) {
        int row = q0 + w * 16 + l15;
        int d   = ks * 32 + g * 8;
        bf16x8 v = *(const bf16x8*)(Qg + (size_t)row * 1536 + d);
        bf16x8 s;
#pragma unroll
        for (int j = 0; j < 8; ++j) s[j] = (__bf16)((float)v[j] * (0.125f * LOG2E));
        qf[ks] = s;
    }

    f32x4 o_acc[4] = {};
    f32x4 l_acc = { 0.f, 0.f, 0.f, 0.f };             // per-lane partial sums (k-slices)
    const int src_row = (lane & 48) + (g << 2);

    asm volatile("s_waitcnt vmcnt(0)" ::: "memory");
    __syncthreads();

    for (int kt = 0; kt < 32; ++kt) {
        const int cur = kt & 1;
        const int k0  = kt * 64;

        // mask loads first (vm ops 1-4): their waitcnt won't drain staging
        f32x4 mv[4];
#pragma unroll
        for (int n = 0; n < 4; ++n)
            mv[n] = *(const f32x4*)(mbase + k0 + n * 16);

        // stage tile t+1 into alt buffer (affine addresses; peeled on last iter)
        if (kt < 31) {
            const size_t ko = (size_t)(kt + 1) * 64 * 1536;
            const size_t vo = (size_t)(kt + 1) * 64;
            const int alt = cur ? 0 : 4096;
            gload_lds16(kg0 + ko, (void*)((u16*)Ks + alt + (ksd0 - (u16*)Ks)));
            gload_lds16(vg0 + vo, (void*)((u16*)Vs + alt + (vsd0 - (u16*)Vs)));
        }

        // S^T = K Q^T (swapped): sa[n] reg r on lane (g,l15) = S'[k=16n+4g+r][q=l15]
        f32x4 sa[4] = {};
        __builtin_amdgcn_s_setprio(1);
#pragma unroll
        for (int ks = 0; ks < 2; ++ks) {
            const int cb = ks * 4 + g;
            bf16x8 bk_[4];
#pragma unroll
            for (int n = 0; n < 4; ++n) {
                int row = n * 16 + l15;
                bk_[n] = *(const bf16x8*)&Ks[cur][row * 64 + ((cb ^ l7) << 3)];
            }
#pragma unroll
            for (int n = 0; n < 4; ++n)
                sa[n] = __builtin_amdgcn_mfma_f32_16x16x32_bf16(bk_[n], qf[ks], sa[n], 0, 0, 0);
        }
        __builtin_amdgcn_s_setprio(0);

        // P = exp2(S + mask*log2e)  (unshifted; bounded scores -> fp32-exact)
#pragma unroll
        for (int n = 0; n < 4; ++n)
#pragma unroll
            for (int r = 0; r < 4; ++r)
                sa[n][r] = __builtin_amdgcn_exp2f(fmaf(mv[n][r], LOG2E, sa[n][r]));

        // per-lane partial row-sum (no cross-lane work in-loop)
        l_acc += (sa[0] + sa[1]) + (sa[2] + sa[3]);

        // lane-local A-fragments for PV (k-permutation baked into VT layout)
        bf16x8 pfrag[2];
#pragma unroll
        for (int ks2 = 0; ks2 < 2; ++ks2) {
            bf16x8 t;
            t[0] = (__bf16)sa[2 * ks2][0]; t[1] = (__bf16)sa[2 * ks2][1];
            t[2] = (__bf16)sa[2 * ks2][2]; t[3] = (__bf16)sa[2 * ks2][3];
            t[4] = (__bf16)sa[2 * ks2 + 1][0]; t[5] = (__bf16)sa[2 * ks2 + 1][1];
            t[6] = (__bf16)sa[2 * ks2 + 1][2]; t[7] = (__bf16)sa[2 * ks2 + 1][3];
            pfrag[ks2] = t;
        }

        // O += P @ V  (single b128 V reads, conflict-free)
        __builtin_amdgcn_s_setprio(1);
#pragma unroll
        for (int ks2 = 0; ks2 < 2; ++ks2) {
            const int sc = ((ks2 * 4 + g) ^ l7) << 3;
#pragma unroll
            for (int dn = 0; dn < 4; ++dn) {
                bf16x8 vb = *(const bf16x8*)&Vs[cur][(dn * 16 + l15) * 64 + sc];
                o_acc[dn] = __builtin_amdgcn_mfma_f32_16x16x32_bf16(pfrag[ks2], vb, o_acc[dn], 0, 0, 0);
            }
        }
        __builtin_amdgcn_s_setprio(0);

        asm volatile("s_waitcnt vmcnt(0)" ::: "memory");
        __syncthreads();
    }

    // epilogue: finish l-reduction (once), normalize, store
    float l_run = (l_acc[0] + l_acc[1]) + (l_acc[2] + l_acc[3]);
    l_run += __shfl_xor(l_run, 16);
    l_run += __shfl_xor(l_run, 32);
#pragma unroll
    for (int r = 0; r < 4; ++r) {
        float lr = __shfl(l_run, src_row + r);
        float inv = 1.f / lr;
#pragma unroll
        for (int dn = 0; dn < 4; ++dn) {
            int row = q0 + w * 16 + (g << 2) + r;
            int col = h * 64 + dn * 16 + l15;
            Comb[(rowbase + row) * 768 + col] = f2b(o_acc[dn][r] * inv);
        }
    }
}

// ---------------- launch ----------------

extern "C" void kernel_launch(void* const* d_in, const int* in_sizes, int n_in,
                              void* d_out, int out_size, void* d_ws, size_t ws_size,
                              hipStream_t stream) {
    (void)in_sizes; (void)n_in; (void)out_size; (void)ws_size;
    const float* x   = (const float*)d_in[0];
    const float* msk = (const float*)d_in[1];
    const float* Wq  = (const float*)d_in[2];
    const float* bq  = (const float*)d_in[3];
    const float* Wk  = (const float*)d_in[4];
    const float* bk  = (const float*)d_in[5];
    const float* Wv  = (const float*)d_in[6];
    const float* bv  = (const float*)d_in[7];
    const float* Wo  = (const float*)d_in[8];
    const float* bo  = (const float*)d_in[9];
    float* out = (float*)d_out;

    u16* WqkvT = (u16*)d_ws;                          // 2304*768
    u16* WoT   = WqkvT + (size_t)2304 * 768;          // 768*768
    u16* QKb   = WoT   + (size_t)768 * 768;           // 8192*1536 (q | k)
    u16* VT    = QKb   + (size_t)8192 * 1536;         // 768*8192 (transposed+permuted V)
    u16* Comb  = VT    + (size_t)768 * 8192;          // 8192*768
    float* bqkv = (float*)(Comb + (size_t)8192 * 768); // 2304

    wprep_kernel<<<dim3(24, 24, 4), dim3(32, 8), 0, stream>>>(
        Wq, Wk, Wv, Wo, bq, bk, bv, WqkvT, WoT, bqkv);

    // QKV projection directly from f32 x (fused cvt); Q/K -> QKb, V -> VT (transposed+permuted)
    gemm_x_kernel<<<dim3(18, 64), 256, 0, stream>>>(
        x, WqkvT, bqkv, QKb, VT, 8192, 2304, 768, 1536);
    attn_kernel<<<dim3(16, 48), 512, 0, stream>>>(QKb, VT, msk, Comb);
    // out = Comb @ WoT^T + bo  (64x128 tiles: 768 blocks = 3/CU)
    gemm_bt64_kernel<<<dim3(6, 128), 256, 0, stream>>>(
        Comb, WoT, bo, out, 8192, 768, 768, 768);
}

// Round 20
// 158.535 us; speedup vs baseline: 1.0897x; 1.0897x over previous
//
#include <hip/hip_runtime.h>
#include <hip/hip_bf16.h>

typedef __bf16 bf16x8 __attribute__((ext_vector_type(8)));
typedef __bf16 bf16x4 __attribute__((ext_vector_type(4)));
typedef float  f32x4  __attribute__((ext_vector_type(4)));
typedef unsigned short u16;
typedef unsigned int   u32;

#define GLOBAL_AS __attribute__((address_space(1)))
#define LDS_AS    __attribute__((address_space(3)))

#define LOG2E 1.44269504088896f

__device__ __forceinline__ void gload_lds16(const void* g, void* l) {
    __builtin_amdgcn_global_load_lds((GLOBAL_AS void*)g, (LDS_AS void*)l, 16, 0, 0);
}

__device__ __forceinline__ u16 f2b(float f) {
    union { float f; u32 u; } c; c.f = f;
    u32 u = c.u;
    u32 r = (u + 0x7FFFu + ((u >> 16) & 1u)) >> 16;   // RNE
    return (u16)r;
}

// XCD-locality block remap (bijective; assumes HW round-robin dispatch -> XCD = flat%8,
// perf-only heuristic). Blocks sharing a Y-panel land on one XCD. Requires gridDim.y%8==0.
__device__ __forceinline__ int2 xcd_remap() {
    int j   = blockIdx.x + blockIdx.y * gridDim.x;
    int xcd = j & 7, s = j >> 3;
    int by  = xcd * (gridDim.y >> 3) + s / gridDim.x;
    int bx  = s % gridDim.x;
    return make_int2(bx, by);
}

// ---------------- conversion kernels ----------------

__global__ void cvt_x_kernel(const float* __restrict__ x, u16* __restrict__ out, int n4) {
    int i = blockIdx.x * blockDim.x + threadIdx.x;
    if (i < n4) {
        float4 v = ((const float4*)x)[i];
        u16 o[4] = { f2b(v.x), f2b(v.y), f2b(v.z), f2b(v.w) };
        ((uint2*)out)[i] = *(uint2*)o;
    }
}

// All 4 weight transposes (768x768 f32 -> bf16, dst[j][k]=src[k][j]) + bias pack in ONE launch.
__global__ void wprep_kernel(const float* __restrict__ Wq, const float* __restrict__ Wk,
                             const float* __restrict__ Wv, const float* __restrict__ Wo,
                             const float* __restrict__ bq, const float* __restrict__ bk,
                             const float* __restrict__ bv,
                             u16* __restrict__ WqkvT, u16* __restrict__ WoT,
                             float* __restrict__ bqkv) {
    __shared__ float tile[32][33];
    const int z = blockIdx.z;
    const float* src = (z == 0) ? Wq : (z == 1) ? Wk : (z == 2) ? Wv : Wo;
    u16* dst = (z == 3) ? WoT : WqkvT + (size_t)z * 768 * 768;
    int jt = blockIdx.x * 32, kt = blockIdx.y * 32;
    int tx = threadIdx.x, ty = threadIdx.y;           // block (32,8)
#pragma unroll
    for (int i = 0; i < 4; ++i)
        tile[ty + i * 8][tx] = src[(size_t)(kt + ty + i * 8) * 768 + jt + tx];
    __syncthreads();
#pragma unroll
    for (int i = 0; i < 4; ++i)
        dst[(size_t)(jt + ty + i * 8) * 768 + kt + tx] = f2b(tile[tx][ty + i * 8]);
    if (z == 0 && blockIdx.x == 0 && blockIdx.y == 0) {
        for (int i = ty * 32 + tx; i < 2304; i += 256)
            bqkv[i] = (i < 768) ? bq[i] : (i < 1536 ? bk[i - 768] : bv[i - 1536]);
    }
}

// ---------------- GEMM 128x128: C[M][ldc] = A[M][K] @ Bt[N][K]^T + bias ----------------
// LDS tiles XOR-swizzled (chunk ^ (row&7)). XCD-remapped blocks (A-panel locality).
// VSPLIT: cols [0,1536) -> C; cols [1536,2304) -> VT[col-1536][perm(row)], perm within
// each 64-block: p = (r&35) + ((r&12)<<1) + ((r&16)>>2)  (bakes the PV k-permutation).
template <typename OutT, bool VSPLIT>
__global__ __launch_bounds__(256) void gemm_bt_kernel(
    const u16* __restrict__ A, const u16* __restrict__ Bt,
    const float* __restrict__ bias, OutT* __restrict__ C, u16* __restrict__ VT,
    int M, int N, int K, int ldc)
{
    __shared__ u16 As[128 * 64];
    __shared__ u16 Bs[128 * 64];
    const int lane = threadIdx.x & 63;
    const int w    = threadIdx.x >> 6;
    const int g    = lane >> 4;
    const int l15  = lane & 15;
    const int wr   = w >> 1, wc = w & 1;              // 2x2 waves -> 64x64 each
    const int2 bc  = xcd_remap();
    const int m0   = bc.y * 128, n0 = bc.x * 128;

    f32x4 acc[4][4] = {};

    for (int k0 = 0; k0 < K; k0 += 64) {
        __syncthreads();
#pragma unroll
        for (int i = 0; i < 4; ++i) {
            int ci0 = w * 64 + i * 256;               // wave-uniform chunk base
            int ci  = ci0 + lane;
            int row = ci >> 3;
            int col = ((ci & 7) ^ (row & 7)) << 3;    // pre-swizzled source
            gload_lds16(A  + (size_t)(m0 + row) * K + k0 + col, (void*)(As + ci0 * 8));
            gload_lds16(Bt + (size_t)(n0 + row) * K + k0 + col, (void*)(Bs + ci0 * 8));
        }
        asm volatile("s_waitcnt vmcnt(0)" ::: "memory");
        __syncthreads();

#pragma unroll
        for (int ks = 0; ks < 2; ++ks) {
            const int cb = ks * 4 + g;                // chunk index of this fragment
            bf16x8 af[4], bfr[4];
#pragma unroll
            for (int i = 0; i < 4; ++i) {
                int row = wr * 64 + i * 16 + l15;
                af[i] = *(const bf16x8*)&As[row * 64 + ((cb ^ (row & 7)) << 3)];
            }
#pragma unroll
            for (int j = 0; j < 4; ++j) {
                int row = wc * 64 + j * 16 + l15;
                bfr[j] = *(const bf16x8*)&Bs[row * 64 + ((cb ^ (row & 7)) << 3)];
            }
#pragma unroll
            for (int i = 0; i < 4; ++i)
#pragma unroll
                for (int j = 0; j < 4; ++j)
                    acc[i][j] = __builtin_amdgcn_mfma_f32_16x16x32_bf16(af[i], bfr[j], acc[i][j], 0, 0, 0);
        }
    }

    const bool vblk = VSPLIT && (n0 >= 1536);         // uniform per block (1536 % 128 == 0)
#pragma unroll
    for (int j = 0; j < 4; ++j) {
        int col = n0 + wc * 64 + j * 16 + l15;
        float bv = bias[col];
#pragma unroll
        for (int i = 0; i < 4; ++i) {
            int row = m0 + wr * 64 + i * 16 + (g << 2);
            if (vblk) {
                u16 o[4];
#pragma unroll
                for (int r = 0; r < 4; ++r) o[r] = f2b(acc[i][j][r] + bv);
                int rl = row & 63;
                int pr = (row & ~63) + (rl & 35) + ((rl & 12) << 1) + ((rl & 16) >> 2);
                *(uint2*)(VT + (size_t)(col - 1536) * 8192 + pr) = *(uint2*)o;
            } else {
#pragma unroll
                for (int r = 0; r < 4; ++r) {
                    float v = acc[i][j][r] + bv;
                    if constexpr (sizeof(OutT) == 2)
                        C[(size_t)(row + r) * ldc + col] = (OutT)f2b(v);
                    else
                        C[(size_t)(row + r) * ldc + col] = (OutT)v;
                }
            }
        }
    }
}

// ---------------- GEMM 64x128 (f32 out), XOR-swizzled LDS, XCD-remapped, DBUF ----------
// Grid 768 = 3 blocks/CU; LDS 48 KB -> capacity 3 (same residency as single-buffer, which
// was grid-limited at 3) -> dbuf is pure latency hiding: stage(k+1) overlaps compute(k).
__global__ __launch_bounds__(256) void gemm_bt64_kernel(
    const u16* __restrict__ A, const u16* __restrict__ Bt,
    const float* __restrict__ bias, float* __restrict__ C,
    int M, int N, int K, int ldc)
{
    __shared__ u16 As[2][64 * 64];                    // 16 KB
    __shared__ u16 Bs[2][128 * 64];                   // 32 KB
    const int lane = threadIdx.x & 63;
    const int w    = threadIdx.x >> 6;
    const int g    = lane >> 4;
    const int l15  = lane & 15;
    const int wr   = w >> 1, wc = w & 1;              // 2x2 waves -> 32x64 each
    const int2 bc  = xcd_remap();
    const int m0   = bc.y * 64, n0 = bc.x * 128;

    f32x4 acc[2][4] = {};

    // per-lane staging addresses (affine in k0)
    const int aci  = w * 64 + lane;                   // A chunk 0..255 (x2 instrs = 512)
    const int arow = aci >> 3;
    const int acol = ((aci & 7) ^ (arow & 7)) << 3;

    // prologue: stage k-tile 0 into buffer 0
#pragma unroll
    for (int i = 0; i < 2; ++i) {
        int ci = aci + i * 256;
        int row = ci >> 3, col = ((ci & 7) ^ (row & 7)) << 3;
        gload_lds16(A + (size_t)(m0 + row) * K + col, (void*)(As[0] + (w * 64 + i * 256) * 8));
    }
#pragma unroll
    for (int i = 0; i < 4; ++i) {
        int ci = aci + i * 256;
        int row = ci >> 3, col = ((ci & 7) ^ (row & 7)) << 3;
        gload_lds16(Bt + (size_t)(n0 + row) * K + col, (void*)(Bs[0] + (w * 64 + i * 256) * 8));
    }
    asm volatile("s_waitcnt vmcnt(0)" ::: "memory");
    __syncthreads();

    const int NK = K / 64;
    for (int t = 0; t < NK; ++t) {
        const int cur = t & 1;
        // stage k-tile t+1 into alt buffer (overlaps with compute below)
        if (t < NK - 1) {
            const int k0n = (t + 1) * 64;
#pragma unroll
            for (int i = 0; i < 2; ++i) {
                int ci = aci + i * 256;
                int row = ci >> 3, col = ((ci & 7) ^ (row & 7)) << 3;
                gload_lds16(A + (size_t)(m0 + row) * K + k0n + col,
                            (void*)(As[cur ^ 1] + (w * 64 + i * 256) * 8));
            }
#pragma unroll
            for (int i = 0; i < 4; ++i) {
                int ci = aci + i * 256;
                int row = ci >> 3, col = ((ci & 7) ^ (row & 7)) << 3;
                gload_lds16(Bt + (size_t)(n0 + row) * K + k0n + col,
                            (void*)(Bs[cur ^ 1] + (w * 64 + i * 256) * 8));
            }
        }

#pragma unroll
        for (int ks = 0; ks < 2; ++ks) {
            const int cb = ks * 4 + g;
            bf16x8 af[2], bfr[4];
#pragma unroll
            for (int i = 0; i < 2; ++i) {
                int row = wr * 32 + i * 16 + l15;
                af[i] = *(const bf16x8*)&As[cur][row * 64 + ((cb ^ (row & 7)) << 3)];
            }
#pragma unroll
            for (int j = 0; j < 4; ++j) {
                int row = wc * 64 + j * 16 + l15;
                bfr[j] = *(const bf16x8*)&Bs[cur][row * 64 + ((cb ^ (row & 7)) << 3)];
            }
#pragma unroll
            for (int i = 0; i < 2; ++i)
#pragma unroll
                for (int j = 0; j < 4; ++j)
                    acc[i][j] = __builtin_amdgcn_mfma_f32_16x16x32_bf16(af[i], bfr[j], acc[i][j], 0, 0, 0);
        }

        asm volatile("s_waitcnt vmcnt(0)" ::: "memory");
        __syncthreads();
    }

#pragma unroll
    for (int j = 0; j < 4; ++j) {
        int col = n0 + wc * 64 + j * 16 + l15;
        float bv = bias[col];
#pragma unroll
        for (int i = 0; i < 2; ++i) {
            int row = m0 + wr * 32 + i * 16 + (g << 2);
#pragma unroll
            for (int r = 0; r < 4; ++r)
                C[(size_t)(row + r) * ldc + col] = acc[i][j][r] + bv;
        }
    }
}

// ---------------- flash attention (R16 exact: best known, 89-92 us) ----------------
// 512-thread blocks (8 waves x 16 q), QBLK=128, KVBLK=64, grid (16,48)=768 = 3 blocks/CU,
// LDS 32 KB (capacity 5). XCD remap: K/V L2-resident (FETCH 18.5 MB). Swapped QK^T,
// lane-local P via permuted VT, unshifted exp2 softmax, dbuf K/V, 1 barrier/iter,
// zero bank conflicts, static LDS indexing.
__global__ __launch_bounds__(512) void attn_kernel(
    const u16* __restrict__ QK, const u16* __restrict__ VT,
    const float* __restrict__ mask, u16* __restrict__ Comb)
{
    __shared__ u16 Ks[2][64 * 64];     // 16 KB
    __shared__ u16 Vs[2][64 * 64];     // 16 KB  -> total 32 KB
    const int lane = threadIdx.x & 63;
    const int w    = threadIdx.x >> 6;                // 0..7
    const int g    = lane >> 4;
    const int l15  = lane & 15;
    const int l7   = lane & 7;
    const int2 bc  = xcd_remap();
    const int q0   = bc.x * 128;
    const int bh   = bc.y;
    const int b    = bh / 12, h = bh % 12;
    const size_t rowbase = (size_t)b * 2048;
    const u16* Qg = QK + rowbase * 1536 + h * 64;
    const u16* Kg = QK + rowbase * 1536 + 768 + h * 64;
    const u16* Vg = VT + (size_t)(h * 64) * 8192 + b * 2048;  // row d (stride 8192), col s'
    const float* mbase = mask + b * 2048 + (g << 2);

    // staging: 512 threads cover 512 chunks (one 16B chunk each)
    const int sci  = threadIdx.x;
    const int srow = sci >> 3;                        // k-row / d-row
    const int kc   = ((sci & 7) ^ (srow & 7)) << 3;   // swizzle col
    const u16* kg0 = Kg + (size_t)srow * 1536 + kc;
    const u16* vg0 = Vg + (size_t)srow * 8192 + kc;
    u16* const ksd0 = (u16*)Ks + (w * 64) * 8;        // wave-uniform base + lane*16B
    u16* const vsd0 = (u16*)Vs + (w * 64) * 8;

    // prologue: stage K/V tile 0
    gload_lds16(kg0, (void*)ksd0);
    gload_lds16(vg0, (void*)vsd0);

    // Q fragments scaled by 0.125 * log2(e); wave owns rows q0 + w*16 .. +15
    bf16x8 qf[2];
#pragma unroll
    for (int ks = 0; ks < 2; ++ks) {
        int row = q0 + w * 16 + l15;
        int d   = ks * 32 + g * 8;
        bf16x8 v = *(const bf16x8*)(Qg + (size_t)row * 1536 + d);
        bf16x8 s;
#pragma unroll
        for (int j = 0; j < 8; ++j) s[j] = (__bf16)((float)v[j] * (0.125f * LOG2E));
        qf[ks] = s;
    }

    f32x4 o_acc[4] = {};
    f32x4 l_acc = { 0.f, 0.f, 0.f, 0.f };             // per-lane partial sums (k-slices)
    const int src_row = (lane & 48) + (g << 2);

    asm volatile("s_waitcnt vmcnt(0)" ::: "memory");
    __syncthreads();

    for (int kt = 0; kt < 32; ++kt) {
        const int cur = kt & 1;
        const int k0  = kt * 64;

        // mask loads first (vm ops 1-4): their waitcnt won't drain staging
        f32x4 mv[4];
#pragma unroll
        for (int n = 0; n < 4; ++n)
            mv[n] = *(const f32x4*)(mbase + k0 + n * 16);

        // stage tile t+1 into alt buffer (affine addresses; peeled on last iter)
        if (kt < 31) {
            const size_t ko = (size_t)(kt + 1) * 64 * 1536;
            const size_t vo = (size_t)(kt + 1) * 64;
            const int alt = cur ? 0 : 4096;
            gload_lds16(kg0 + ko, (void*)((u16*)Ks + alt + (ksd0 - (u16*)Ks)));
            gload_lds16(vg0 + vo, (void*)((u16*)Vs + alt + (vsd0 - (u16*)Vs)));
        }

        // S^T = K Q^T (swapped): sa[n] reg r on lane (g,l15) = S'[k=16n+4g+r][q=l15]
        f32x4 sa[4] = {};
        __builtin_amdgcn_s_setprio(1);
#pragma unroll
        for (int ks = 0; ks < 2; ++ks) {
            const int cb = ks * 4 + g;
            bf16x8 bk_[4];
#pragma unroll
            for (int n = 0; n < 4; ++n) {
                int row = n * 16 + l15;
                bk_[n] = *(const bf16x8*)&Ks[cur][row * 64 + ((cb ^ l7) << 3)];
            }
#pragma unroll
            for (int n = 0; n < 4; ++n)
                sa[n] = __builtin_amdgcn_mfma_f32_16x16x32_bf16(bk_[n], qf[ks], sa[n], 0, 0, 0);
        }
        __builtin_amdgcn_s_setprio(0);

        // P = exp2(S + mask*log2e)  (unshifted; bounded scores -> fp32-exact)
#pragma unroll
        for (int n = 0; n < 4; ++n)
#pragma unroll
            for (int r = 0; r < 4; ++r)
                sa[n][r] = __builtin_amdgcn_exp2f(fmaf(mv[n][r], LOG2E, sa[n][r]));

        // per-lane partial row-sum (no cross-lane work in-loop)
        l_acc += (sa[0] + sa[1]) + (sa[2] + sa[3]);

        // lane-local A-fragments for PV (k-permutation baked into VT layout)
        bf16x8 pfrag[2];
#pragma unroll
        for (int ks2 = 0; ks2 < 2; ++ks2) {
            bf16x8 t;
            t[0] = (__bf16)sa[2 * ks2][0]; t[1] = (__bf16)sa[2 * ks2][1];
            t[2] = (__bf16)sa[2 * ks2][2]; t[3] = (__bf16)sa[2 * ks2][3];
            t[4] = (__bf16)sa[2 * ks2 + 1][0]; t[5] = (__bf16)sa[2 * ks2 + 1][1];
            t[6] = (__bf16)sa[2 * ks2 + 1][2]; t[7] = (__bf16)sa[2 * ks2 + 1][3];
            pfrag[ks2] = t;
        }

        // O += P @ V  (single b128 V reads, conflict-free)
        __builtin_amdgcn_s_setprio(1);
#pragma unroll
        for (int ks2 = 0; ks2 < 2; ++ks2) {
            const int sc = ((ks2 * 4 + g) ^ l7) << 3;
#pragma unroll
            for (int dn = 0; dn < 4; ++dn) {
                bf16x8 vb = *(const bf16x8*)&Vs[cur][(dn * 16 + l15) * 64 + sc];
                o_acc[dn] = __builtin_amdgcn_mfma_f32_16x16x32_bf16(pfrag[ks2], vb, o_acc[dn], 0, 0, 0);
            }
        }
        __builtin_amdgcn_s_setprio(0);

        asm volatile("s_waitcnt vmcnt(0)" ::: "memory");
        __syncthreads();
    }

    // epilogue: finish l-reduction (once), normalize, store
    float l_run = (l_acc[0] + l_acc[1]) + (l_acc[2] + l_acc[3]);
    l_run += __shfl_xor(l_run, 16);
    l_run += __shfl_xor(l_run, 32);
#pragma unroll
    for (int r = 0; r < 4; ++r) {
        float lr = __shfl(l_run, src_row + r);
        float inv = 1.f / lr;
#pragma unroll
        for (int dn = 0; dn < 4; ++dn) {
            int row = q0 + w * 16 + (g << 2) + r;
            int col = h * 64 + dn * 16 + l15;
            Comb[(rowbase + row) * 768 + col] = f2b(o_acc[dn][r] * inv);
        }
    }
}

// ---------------- launch ----------------

extern "C" void kernel_launch(void* const* d_in, const int* in_sizes, int n_in,
                              void* d_out, int out_size, void* d_ws, size_t ws_size,
                              hipStream_t stream) {
    (void)in_sizes; (void)n_in; (void)out_size; (void)ws_size;
    const float* x   = (const float*)d_in[0];
    const float* msk = (const float*)d_in[1];
    const float* Wq  = (const float*)d_in[2];
    const float* bq  = (const float*)d_in[3];
    const float* Wk  = (const float*)d_in[4];
    const float* bk  = (const float*)d_in[5];
    const float* Wv  = (const float*)d_in[6];
    const float* bv  = (const float*)d_in[7];
    const float* Wo  = (const float*)d_in[8];
    const float* bo  = (const float*)d_in[9];
    float* out = (float*)d_out;

    u16* Xb    = (u16*)d_ws;                          // 8192*768
    u16* WqkvT = Xb    + (size_t)8192 * 768;          // 2304*768
    u16* WoT   = WqkvT + (size_t)2304 * 768;          // 768*768
    u16* QKb   = WoT   + (size_t)768 * 768;           // 8192*1536 (q | k)
    u16* VT    = QKb   + (size_t)8192 * 1536;         // 768*8192 (transposed+permuted V)
    u16* Comb  = VT    + (size_t)768 * 8192;          // 8192*768
    float* bqkv = (float*)(Comb + (size_t)8192 * 768); // 2304

    cvt_x_kernel<<<6144, 256, 0, stream>>>(x, Xb, 8192 * 768 / 4);
    wprep_kernel<<<dim3(24, 24, 4), dim3(32, 8), 0, stream>>>(
        Wq, Wk, Wv, Wo, bq, bk, bv, WqkvT, WoT, bqkv);

    // QKV projection; Q/K -> QKb (ldc 1536), V -> VT transposed+permuted (fused)
    gemm_bt_kernel<u16, true><<<dim3(18, 64), 256, 0, stream>>>(
        Xb, WqkvT, bqkv, QKb, VT, 8192, 2304, 768, 1536);
    attn_kernel<<<dim3(16, 48), 512, 0, stream>>>(QKb, VT, msk, Comb);
    // out = Comb @ WoT^T + bo  (64x128 tiles: 768 blocks = 3/CU, dbuf LDS)
    gemm_bt64_kernel<<<dim3(6, 128), 256, 0, stream>>>(
        Comb, WoT, bo, out, 8192, 768, 768, 768);
}

// Round 21
// 157.117 us; speedup vs baseline: 1.0996x; 1.0090x over previous
//
#include <hip/hip_runtime.h>
#include <hip/hip_bf16.h>

typedef __bf16 bf16x8 __attribute__((ext_vector_type(8)));
typedef __bf16 bf16x4 __attribute__((ext_vector_type(4)));
typedef float  f32x4  __attribute__((ext_vector_type(4)));
typedef unsigned short u16;
typedef unsigned int   u32;

#define GLOBAL_AS __attribute__((address_space(1)))
#define LDS_AS    __attribute__((address_space(3)))

#define LOG2E 1.44269504088896f

__device__ __forceinline__ void gload_lds16(const void* g, void* l) {
    __builtin_amdgcn_global_load_lds((GLOBAL_AS void*)g, (LDS_AS void*)l, 16, 0, 0);
}

__device__ __forceinline__ u16 f2b(float f) {
    union { float f; u32 u; } c; c.f = f;
    u32 u = c.u;
    u32 r = (u + 0x7FFFu + ((u >> 16) & 1u)) >> 16;   // RNE
    return (u16)r;
}

// XCD-locality block remap (bijective; assumes HW round-robin dispatch -> XCD = flat%8,
// perf-only heuristic). Blocks sharing a Y-panel land on one XCD. Requires gridDim.y%8==0.
__device__ __forceinline__ int2 xcd_remap() {
    int j   = blockIdx.x + blockIdx.y * gridDim.x;
    int xcd = j & 7, s = j >> 3;
    int by  = xcd * (gridDim.y >> 3) + s / gridDim.x;
    int bx  = s % gridDim.x;
    return make_int2(bx, by);
}

// ---------------- prep: x cvt (f32->bf16) + 4 weight transposes + bias pack, ONE launch ----
// blocks [0,6144): cvt_x role (elementwise, 1024 f32/block).
// blocks [6144,8448): weight-transpose role; wb = bid-6144, z = wb/576 selects W{q,k,v,o};
// 32x32 tile transpose via LDS, (32,8) logical thread shape from flat tid.
__global__ __launch_bounds__(256) void prep_kernel(
    const float* __restrict__ x, u16* __restrict__ Xb,
    const float* __restrict__ Wq, const float* __restrict__ Wk,
    const float* __restrict__ Wv, const float* __restrict__ Wo,
    const float* __restrict__ bq, const float* __restrict__ bk,
    const float* __restrict__ bv,
    u16* __restrict__ WqkvT, u16* __restrict__ WoT, float* __restrict__ bqkv)
{
    __shared__ float tile[32][33];
    const int bid = blockIdx.x;
    const int tid = threadIdx.x;

    if (bid < 6144) {                                 // cvt_x: 6144*256*4 = 8192*768 elems
        int i = bid * 256 + tid;
        float4 v = ((const float4*)x)[i];
        u16 o[4] = { f2b(v.x), f2b(v.y), f2b(v.z), f2b(v.w) };
        ((uint2*)Xb)[i] = *(uint2*)o;
        return;
    }

    const int wb = bid - 6144;                        // 0..2303
    const int z  = wb / 576;                          // weight index
    const int r  = wb % 576;
    const int bx = r % 24, by = r / 24;
    const float* src = (z == 0) ? Wq : (z == 1) ? Wk : (z == 2) ? Wv : Wo;
    u16* dst = (z == 3) ? WoT : WqkvT + (size_t)z * 768 * 768;
    const int jt = bx * 32, kt = by * 32;
    const int tx = tid & 31, ty = tid >> 5;           // (32,8) logical
#pragma unroll
    for (int i = 0; i < 4; ++i)
        tile[ty + i * 8][tx] = src[(size_t)(kt + ty + i * 8) * 768 + jt + tx];
    __syncthreads();
#pragma unroll
    for (int i = 0; i < 4; ++i)
        dst[(size_t)(jt + ty + i * 8) * 768 + kt + tx] = f2b(tile[tx][ty + i * 8]);
    if (z == 0 && bx == 0 && by == 0) {
        for (int i = tid; i < 2304; i += 256)
            bqkv[i] = (i < 768) ? bq[i] : (i < 1536 ? bk[i - 768] : bv[i - 1536]);
    }
}

// ---------------- GEMM 128x128: C[M][ldc] = A[M][K] @ Bt[N][K]^T + bias ----------------
// LDS tiles XOR-swizzled (chunk ^ (row&7)). XCD-remapped blocks (A-panel locality).
// VSPLIT: cols [0,1536) -> C; cols [1536,2304) -> VT[col-1536][perm(row)], perm within
// each 64-block: p = (r&35) + ((r&12)<<1) + ((r&16)>>2)  (bakes the PV k-permutation).
template <typename OutT, bool VSPLIT>
__global__ __launch_bounds__(256) void gemm_bt_kernel(
    const u16* __restrict__ A, const u16* __restrict__ Bt,
    const float* __restrict__ bias, OutT* __restrict__ C, u16* __restrict__ VT,
    int M, int N, int K, int ldc)
{
    __shared__ u16 As[128 * 64];
    __shared__ u16 Bs[128 * 64];
    const int lane = threadIdx.x & 63;
    const int w    = threadIdx.x >> 6;
    const int g    = lane >> 4;
    const int l15  = lane & 15;
    const int wr   = w >> 1, wc = w & 1;              // 2x2 waves -> 64x64 each
    const int2 bc  = xcd_remap();
    const int m0   = bc.y * 128, n0 = bc.x * 128;

    f32x4 acc[4][4] = {};

    for (int k0 = 0; k0 < K; k0 += 64) {
        __syncthreads();
#pragma unroll
        for (int i = 0; i < 4; ++i) {
            int ci0 = w * 64 + i * 256;               // wave-uniform chunk base
            int ci  = ci0 + lane;
            int row = ci >> 3;
            int col = ((ci & 7) ^ (row & 7)) << 3;    // pre-swizzled source
            gload_lds16(A  + (size_t)(m0 + row) * K + k0 + col, (void*)(As + ci0 * 8));
            gload_lds16(Bt + (size_t)(n0 + row) * K + k0 + col, (void*)(Bs + ci0 * 8));
        }
        asm volatile("s_waitcnt vmcnt(0)" ::: "memory");
        __syncthreads();

#pragma unroll
        for (int ks = 0; ks < 2; ++ks) {
            const int cb = ks * 4 + g;                // chunk index of this fragment
            bf16x8 af[4], bfr[4];
#pragma unroll
            for (int i = 0; i < 4; ++i) {
                int row = wr * 64 + i * 16 + l15;
                af[i] = *(const bf16x8*)&As[row * 64 + ((cb ^ (row & 7)) << 3)];
            }
#pragma unroll
            for (int j = 0; j < 4; ++j) {
                int row = wc * 64 + j * 16 + l15;
                bfr[j] = *(const bf16x8*)&Bs[row * 64 + ((cb ^ (row & 7)) << 3)];
            }
#pragma unroll
            for (int i = 0; i < 4; ++i)
#pragma unroll
                for (int j = 0; j < 4; ++j)
                    acc[i][j] = __builtin_amdgcn_mfma_f32_16x16x32_bf16(af[i], bfr[j], acc[i][j], 0, 0, 0);
        }
    }

    const bool vblk = VSPLIT && (n0 >= 1536);         // uniform per block (1536 % 128 == 0)
#pragma unroll
    for (int j = 0; j < 4; ++j) {
        int col = n0 + wc * 64 + j * 16 + l15;
        float bv = bias[col];
#pragma unroll
        for (int i = 0; i < 4; ++i) {
            int row = m0 + wr * 64 + i * 16 + (g << 2);
            if (vblk) {
                u16 o[4];
#pragma unroll
                for (int r = 0; r < 4; ++r) o[r] = f2b(acc[i][j][r] + bv);
                int rl = row & 63;
                int pr = (row & ~63) + (rl & 35) + ((rl & 12) << 1) + ((rl & 16) >> 2);
                *(uint2*)(VT + (size_t)(col - 1536) * 8192 + pr) = *(uint2*)o;
            } else {
#pragma unroll
                for (int r = 0; r < 4; ++r) {
                    float v = acc[i][j][r] + bv;
                    if constexpr (sizeof(OutT) == 2)
                        C[(size_t)(row + r) * ldc + col] = (OutT)f2b(v);
                    else
                        C[(size_t)(row + r) * ldc + col] = (OutT)v;
                }
            }
        }
    }
}

// ---------------- GEMM 64x128 (f32 out), XOR-swizzled LDS, XCD-remapped, DBUF ----------
__global__ __launch_bounds__(256) void gemm_bt64_kernel(
    const u16* __restrict__ A, const u16* __restrict__ Bt,
    const float* __restrict__ bias, float* __restrict__ C,
    int M, int N, int K, int ldc)
{
    __shared__ u16 As[2][64 * 64];                    // 16 KB
    __shared__ u16 Bs[2][128 * 64];                   // 32 KB
    const int lane = threadIdx.x & 63;
    const int w    = threadIdx.x >> 6;
    const int g    = lane >> 4;
    const int l15  = lane & 15;
    const int wr   = w >> 1, wc = w & 1;              // 2x2 waves -> 32x64 each
    const int2 bc  = xcd_remap();
    const int m0   = bc.y * 64, n0 = bc.x * 128;

    f32x4 acc[2][4] = {};

    const int aci  = w * 64 + lane;

    // prologue: stage k-tile 0 into buffer 0
#pragma unroll
    for (int i = 0; i < 2; ++i) {
        int ci = aci + i * 256;
        int row = ci >> 3, col = ((ci & 7) ^ (row & 7)) << 3;
        gload_lds16(A + (size_t)(m0 + row) * K + col, (void*)(As[0] + (w * 64 + i * 256) * 8));
    }
#pragma unroll
    for (int i = 0; i < 4; ++i) {
        int ci = aci + i * 256;
        int row = ci >> 3, col = ((ci & 7) ^ (row & 7)) << 3;
        gload_lds16(Bt + (size_t)(n0 + row) * K + col, (void*)(Bs[0] + (w * 64 + i * 256) * 8));
    }
    asm volatile("s_waitcnt vmcnt(0)" ::: "memory");
    __syncthreads();

    const int NK = K / 64;
    for (int t = 0; t < NK; ++t) {
        const int cur = t & 1;
        if (t < NK - 1) {
            const int k0n = (t + 1) * 64;
#pragma unroll
            for (int i = 0; i < 2; ++i) {
                int ci = aci + i * 256;
                int row = ci >> 3, col = ((ci & 7) ^ (row & 7)) << 3;
                gload_lds16(A + (size_t)(m0 + row) * K + k0n + col,
                            (void*)(As[cur ^ 1] + (w * 64 + i * 256) * 8));
            }
#pragma unroll
            for (int i = 0; i < 4; ++i) {
                int ci = aci + i * 256;
                int row = ci >> 3, col = ((ci & 7) ^ (row & 7)) << 3;
                gload_lds16(Bt + (size_t)(n0 + row) * K + k0n + col,
                            (void*)(Bs[cur ^ 1] + (w * 64 + i * 256) * 8));
            }
        }

#pragma unroll
        for (int ks = 0; ks < 2; ++ks) {
            const int cb = ks * 4 + g;
            bf16x8 af[2], bfr[4];
#pragma unroll
            for (int i = 0; i < 2; ++i) {
                int row = wr * 32 + i * 16 + l15;
                af[i] = *(const bf16x8*)&As[cur][row * 64 + ((cb ^ (row & 7)) << 3)];
            }
#pragma unroll
            for (int j = 0; j < 4; ++j) {
                int row = wc * 64 + j * 16 + l15;
                bfr[j] = *(const bf16x8*)&Bs[cur][row * 64 + ((cb ^ (row & 7)) << 3)];
            }
#pragma unroll
            for (int i = 0; i < 2; ++i)
#pragma unroll
                for (int j = 0; j < 4; ++j)
                    acc[i][j] = __builtin_amdgcn_mfma_f32_16x16x32_bf16(af[i], bfr[j], acc[i][j], 0, 0, 0);
        }

        asm volatile("s_waitcnt vmcnt(0)" ::: "memory");
        __syncthreads();
    }

#pragma unroll
    for (int j = 0; j < 4; ++j) {
        int col = n0 + wc * 64 + j * 16 + l15;
        float bv = bias[col];
#pragma unroll
        for (int i = 0; i < 2; ++i) {
            int row = m0 + wr * 32 + i * 16 + (g << 2);
#pragma unroll
            for (int r = 0; r < 4; ++r)
                C[(size_t)(row + r) * ldc + col] = acc[i][j][r] + bv;
        }
    }
}

// ---------------- flash attention (R16 exact: best known, 89-92 us) ----------------
// 512-thread blocks (8 waves x 16 q), QBLK=128, KVBLK=64, grid (16,48)=768 = 3 blocks/CU,
// LDS 32 KB (capacity 5). XCD remap: K/V L2-resident (FETCH 18.5 MB). Swapped QK^T,
// lane-local P via permuted VT, unshifted exp2 softmax, dbuf K/V, 1 barrier/iter,
// zero bank conflicts, static LDS indexing.
__global__ __launch_bounds__(512) void attn_kernel(
    const u16* __restrict__ QK, const u16* __restrict__ VT,
    const float* __restrict__ mask, u16* __restrict__ Comb)
{
    __shared__ u16 Ks[2][64 * 64];     // 16 KB
    __shared__ u16 Vs[2][64 * 64];     // 16 KB  -> total 32 KB
    const int lane = threadIdx.x & 63;
    const int w    = threadIdx.x >> 6;                // 0..7
    const int g    = lane >> 4;
    const int l15  = lane & 15;
    const int l7   = lane & 7;
    const int2 bc  = xcd_remap();
    const int q0   = bc.x * 128;
    const int bh   = bc.y;
    const int b    = bh / 12, h = bh % 12;
    const size_t rowbase = (size_t)b * 2048;
    const u16* Qg = QK + rowbase * 1536 + h * 64;
    const u16* Kg = QK + rowbase * 1536 + 768 + h * 64;
    const u16* Vg = VT + (size_t)(h * 64) * 8192 + b * 2048;  // row d (stride 8192), col s'
    const float* mbase = mask + b * 2048 + (g << 2);

    // staging: 512 threads cover 512 chunks (one 16B chunk each)
    const int sci  = threadIdx.x;
    const int srow = sci >> 3;                        // k-row / d-row
    const int kc   = ((sci & 7) ^ (srow & 7)) << 3;   // swizzle col
    const u16* kg0 = Kg + (size_t)srow * 1536 + kc;
    const u16* vg0 = Vg + (size_t)srow * 8192 + kc;
    u16* const ksd0 = (u16*)Ks + (w * 64) * 8;        // wave-uniform base + lane*16B
    u16* const vsd0 = (u16*)Vs + (w * 64) * 8;

    // prologue: stage K/V tile 0
    gload_lds16(kg0, (void*)ksd0);
    gload_lds16(vg0, (void*)vsd0);

    // Q fragments scaled by 0.125 * log2(e); wave owns rows q0 + w*16 .. +15
    bf16x8 qf[2];
#pragma unroll
    for (int ks = 0; ks < 2; ++ks) {
        int row = q0 + w * 16 + l15;
        int d   = ks * 32 + g * 8;
        bf16x8 v = *(const bf16x8*)(Qg + (size_t)row * 1536 + d);
        bf16x8 s;
#pragma unroll
        for (int j = 0; j < 8; ++j) s[j] = (__bf16)((float)v[j] * (0.125f * LOG2E));
        qf[ks] = s;
    }

    f32x4 o_acc[4] = {};
    f32x4 l_acc = { 0.f, 0.f, 0.f, 0.f };             // per-lane partial sums (k-slices)
    const int src_row = (lane & 48) + (g << 2);

    asm volatile("s_waitcnt vmcnt(0)" ::: "memory");
    __syncthreads();

    for (int kt = 0; kt < 32; ++kt) {
        const int cur = kt & 1;
        const int k0  = kt * 64;

        // mask loads first (vm ops 1-4): their waitcnt won't drain staging
        f32x4 mv[4];
#pragma unroll
        for (int n = 0; n < 4; ++n)
            mv[n] = *(const f32x4*)(mbase + k0 + n * 16);

        // stage tile t+1 into alt buffer (affine addresses; peeled on last iter)
        if (kt < 31) {
            const size_t ko = (size_t)(kt + 1) * 64 * 1536;
            const size_t vo = (size_t)(kt + 1) * 64;
            const int alt = cur ? 0 : 4096;
            gload_lds16(kg0 + ko, (void*)((u16*)Ks + alt + (ksd0 - (u16*)Ks)));
            gload_lds16(vg0 + vo, (void*)((u16*)Vs + alt + (vsd0 - (u16*)Vs)));
        }

        // S^T = K Q^T (swapped): sa[n] reg r on lane (g,l15) = S'[k=16n+4g+r][q=l15]
        f32x4 sa[4] = {};
        __builtin_amdgcn_s_setprio(1);
#pragma unroll
        for (int ks = 0; ks < 2; ++ks) {
            const int cb = ks * 4 + g;
            bf16x8 bk_[4];
#pragma unroll
            for (int n = 0; n < 4; ++n) {
                int row = n * 16 + l15;
                bk_[n] = *(const bf16x8*)&Ks[cur][row * 64 + ((cb ^ l7) << 3)];
            }
#pragma unroll
            for (int n = 0; n < 4; ++n)
                sa[n] = __builtin_amdgcn_mfma_f32_16x16x32_bf16(bk_[n], qf[ks], sa[n], 0, 0, 0);
        }
        __builtin_amdgcn_s_setprio(0);

        // P = exp2(S + mask*log2e)  (unshifted; bounded scores -> fp32-exact)
#pragma unroll
        for (int n = 0; n < 4; ++n)
#pragma unroll
            for (int r = 0; r < 4; ++r)
                sa[n][r] = __builtin_amdgcn_exp2f(fmaf(mv[n][r], LOG2E, sa[n][r]));

        // per-lane partial row-sum (no cross-lane work in-loop)
        l_acc += (sa[0] + sa[1]) + (sa[2] + sa[3]);

        // lane-local A-fragments for PV (k-permutation baked into VT layout)
        bf16x8 pfrag[2];
#pragma unroll
        for (int ks2 = 0; ks2 < 2; ++ks2) {
            bf16x8 t;
            t[0] = (__bf16)sa[2 * ks2][0]; t[1] = (__bf16)sa[2 * ks2][1];
            t[2] = (__bf16)sa[2 * ks2][2]; t[3] = (__bf16)sa[2 * ks2][3];
            t[4] = (__bf16)sa[2 * ks2 + 1][0]; t[5] = (__bf16)sa[2 * ks2 + 1][1];
            t[6] = (__bf16)sa[2 * ks2 + 1][2]; t[7] = (__bf16)sa[2 * ks2 + 1][3];
            pfrag[ks2] = t;
        }

        // O += P @ V  (single b128 V reads, conflict-free)
        __builtin_amdgcn_s_setprio(1);
#pragma unroll
        for (int ks2 = 0; ks2 < 2; ++ks2) {
            const int sc = ((ks2 * 4 + g) ^ l7) << 3;
#pragma unroll
            for (int dn = 0; dn < 4; ++dn) {
                bf16x8 vb = *(const bf16x8*)&Vs[cur][(dn * 16 + l15) * 64 + sc];
                o_acc[dn] = __builtin_amdgcn_mfma_f32_16x16x32_bf16(pfrag[ks2], vb, o_acc[dn], 0, 0, 0);
            }
        }
        __builtin_amdgcn_s_setprio(0);

        asm volatile("s_waitcnt vmcnt(0)" ::: "memory");
        __syncthreads();
    }

    // epilogue: finish l-reduction (once), normalize, store
    float l_run = (l_acc[0] + l_acc[1]) + (l_acc[2] + l_acc[3]);
    l_run += __shfl_xor(l_run, 16);
    l_run += __shfl_xor(l_run, 32);
#pragma unroll
    for (int r = 0; r < 4; ++r) {
        float lr = __shfl(l_run, src_row + r);
        float inv = 1.f / lr;
#pragma unroll
        for (int dn = 0; dn < 4; ++dn) {
            int row = q0 + w * 16 + (g << 2) + r;
            int col = h * 64 + dn * 16 + l15;
            Comb[(rowbase + row) * 768 + col] = f2b(o_acc[dn][r] * inv);
        }
    }
}

// ---------------- launch ----------------

extern "C" void kernel_launch(void* const* d_in, const int* in_sizes, int n_in,
                              void* d_out, int out_size, void* d_ws, size_t ws_size,
                              hipStream_t stream) {
    (void)in_sizes; (void)n_in; (void)out_size; (void)ws_size;
    const float* x   = (const float*)d_in[0];
    const float* msk = (const float*)d_in[1];
    const float* Wq  = (const float*)d_in[2];
    const float* bq  = (const float*)d_in[3];
    const float* Wk  = (const float*)d_in[4];
    const float* bk  = (const float*)d_in[5];
    const float* Wv  = (const float*)d_in[6];
    const float* bv  = (const float*)d_in[7];
    const float* Wo  = (const float*)d_in[8];
    const float* bo  = (const float*)d_in[9];
    float* out = (float*)d_out;

    u16* Xb    = (u16*)d_ws;                          // 8192*768
    u16* WqkvT = Xb    + (size_t)8192 * 768;          // 2304*768
    u16* WoT   = WqkvT + (size_t)2304 * 768;          // 768*768
    u16* QKb   = WoT   + (size_t)768 * 768;           // 8192*1536 (q | k)
    u16* VT    = QKb   + (size_t)8192 * 1536;         // 768*8192 (transposed+permuted V)
    u16* Comb  = VT    + (size_t)768 * 8192;          // 8192*768
    float* bqkv = (float*)(Comb + (size_t)8192 * 768); // 2304

    // x cvt + weight transposes + bias pack, one overlapped launch
    prep_kernel<<<8448, 256, 0, stream>>>(
        x, Xb, Wq, Wk, Wv, Wo, bq, bk, bv, WqkvT, WoT, bqkv);

    // QKV projection; Q/K -> QKb (ldc 1536), V -> VT transposed+permuted (fused)
    gemm_bt_kernel<u16, true><<<dim3(18, 64), 256, 0, stream>>>(
        Xb, WqkvT, bqkv, QKb, VT, 8192, 2304, 768, 1536);
    attn_kernel<<<dim3(16, 48), 512, 0, stream>>>(QKb, VT, msk, Comb);
    // out = Comb @ WoT^T + bo  (64x128 tiles: 768 blocks = 3/CU, dbuf LDS)
    gemm_bt64_kernel<<<dim3(6, 128), 256, 0, stream>>>(
        Comb, WoT, bo, out, 8192, 768, 768, 768);
}